// Round 3
// baseline (1914.112 us; speedup 1.0000x reference)
//
#include <hip/hip_runtime.h>
#include <hip/hip_bf16.h>

#define F_IN 512
#define BSH   6                    // 64 dest nodes per bucket
#define BNODES (1 << BSH)

// --- coarse histogram: cbin[col>>6]++ ---
__global__ void k_hist(const int* __restrict__ col, int* __restrict__ cbin, int E) {
    int e = blockIdx.x * 256 + threadIdx.x;
    if (e < E) atomicAdd(&cbin[col[e] >> BSH], 1);
}

// --- exclusive scan of cbin (NB <= 2048) -> cbase, and copy to cpos cursors ---
__global__ void k_scanb(const int* __restrict__ cbin, int* __restrict__ cbase,
                        int* __restrict__ cpos, int NB) {
    __shared__ int sm[1024];
    __shared__ int carry;
    int t = threadIdx.x;
    if (t == 0) carry = 0;
    __syncthreads();
    for (int c0 = 0; c0 < NB; c0 += 1024) {
        int i = c0 + t;
        int v = (i < NB) ? cbin[i] : 0;
        sm[t] = v; __syncthreads();
        #pragma unroll
        for (int off = 1; off < 1024; off <<= 1) {
            int xv = (t >= off) ? sm[t - off] : 0;
            __syncthreads();
            sm[t] += xv; __syncthreads();
        }
        if (i < NB) {
            int excl = sm[t] - v + carry;
            cbase[i] = excl;
            cpos[i]  = excl;
        }
        __syncthreads();
        if (t == 0) carry += sm[1023];
        __syncthreads();
    }
}

// --- bin edges into coarse buckets, packed entry = (row<<6)|(col&63) ---
__global__ void k_bin(const int* __restrict__ row, const int* __restrict__ col,
                      int* __restrict__ cpos, int* __restrict__ entries, int E) {
    int e = blockIdx.x * 256 + threadIdx.x;
    if (e < E) {
        int c = col[e];
        int p = atomicAdd(&cpos[c >> BSH], 1);
        entries[p] = (row[e] << BSH) | (c & (BNODES - 1));
    }
}

// --- per-bucket LDS histogram -> dinv = rsqrt(deg+1) ---
__global__ __launch_bounds__(256) void k_bdeg(
    const int* __restrict__ entries, const int* __restrict__ cbase,
    const int* __restrict__ cpos, float* __restrict__ dinv, int n)
{
    __shared__ int cnt[BNODES];
    int b = blockIdx.x, t = threadIdx.x;
    if (t < BNODES) cnt[t] = 0;
    __syncthreads();
    int base = cbase[b], end = cpos[b];     // cpos = bucket end after k_bin
    for (int i = base + t; i < end; i += 256)
        atomicAdd(&cnt[entries[i] & (BNODES - 1)], 1);
    __syncthreads();
    if (t < BNODES) {
        int node = (b << BSH) + t;
        if (node < n) dinv[node] = rsqrtf((float)(cnt[t] + 1));
    }
}

// --- hs = (x @ W1) * dinv[node], wave-per-node, LDS transpose-reduce ---
__global__ __launch_bounds__(256) void k_gemm1(
    const float* __restrict__ x, const float* __restrict__ W1,
    const float* __restrict__ dinv, float* __restrict__ hs, int n)
{
    __shared__ float red[4][64 * 17];
    const int lane = threadIdx.x & 63;
    const int wib  = threadIdx.x >> 6;
    const int wave = blockIdx.x * (blockDim.x >> 6) + wib;
    const int nw   = gridDim.x * (blockDim.x >> 6);
    float* rb = red[wib];

    float w[128];
    #pragma unroll
    for (int i = 0; i < 32; ++i) {
        float4 t = ((const float4*)W1)[lane * 32 + i];
        w[4*i+0] = t.x; w[4*i+1] = t.y; w[4*i+2] = t.z; w[4*i+3] = t.w;
    }
    const int q  = lane >> 4;
    const int jj = lane & 15;

    for (int node = wave; node < n; node += nw) {
        const float4* xr = (const float4*)(x + (size_t)node * F_IN);
        float4 a = xr[lane * 2];
        float4 b = xr[lane * 2 + 1];
        float xs[8] = {a.x, a.y, a.z, a.w, b.x, b.y, b.z, b.w};

        float p[16];
        #pragma unroll
        for (int j = 0; j < 16; ++j) p[j] = 0.f;
        #pragma unroll
        for (int i = 0; i < 8; ++i)
            #pragma unroll
            for (int j = 0; j < 16; ++j)
                p[j] = fmaf(xs[i], w[i * 16 + j], p[j]);

        #pragma unroll
        for (int j = 0; j < 16; ++j) rb[lane * 17 + j] = p[j];
        __asm__ volatile("s_waitcnt lgkmcnt(0)" ::: "memory");
        float s = 0.f;
        #pragma unroll
        for (int i = 0; i < 16; ++i) s += rb[(q * 16 + i) * 17 + jj];
        s += __shfl_down(s, 32);
        s += __shfl_down(s, 16);
        if (lane < 16) hs[node * 16 + jj] = s * dinv[node];
    }
}

// --- bucketed pull aggregation with LDS fp32 atomics ---
// acc[c] = hs[c] + sum_{r in in(c)} hs[r]
__global__ __launch_bounds__(256) void k_gather_b(
    const int* __restrict__ entries, const int* __restrict__ cbase,
    const int* __restrict__ cpos, const float* __restrict__ hs,
    float* __restrict__ acc, int n)
{
    __shared__ float lacc[BNODES * 16];
    int b = blockIdx.x, t = threadIdx.x;
    #pragma unroll
    for (int k = t; k < BNODES * 16; k += 256) lacc[k] = 0.f;
    __syncthreads();

    int base = cbase[b], end = cpos[b];
    int j = t & 15;
    for (int i = base + (t >> 4); i < end; i += 16) {
        int e   = entries[i];
        int r   = e >> BSH;
        int cl  = e & (BNODES - 1);
        atomicAdd(&lacc[cl * 16 + j], hs[r * 16 + j]);
    }
    __syncthreads();

    #pragma unroll
    for (int k = t; k < BNODES * 16; k += 256) {
        int node = (b << BSH) + (k >> 4);
        if (node < n) acc[node * 16 + (k & 15)] = lacc[k] + hs[node * 16 + (k & 15)];
    }
}

// --- layer-2: v = relu(acc*dinv + b1); hs2 = (v @ W2) * dinv ---
__global__ void k_gemm2(const float* __restrict__ acc, float* __restrict__ hs2,
                        const float* __restrict__ dinv,
                        const float* __restrict__ b1, const float* __restrict__ W2,
                        int n)
{
    int t = blockIdx.x * blockDim.x + threadIdx.x;
    int node = t >> 4, j = t & 15;
    if (node >= n) return;
    float di = dinv[node];
    float v = fmaxf(acc[node * 16 + j] * di + b1[j], 0.f);
    float h2 = 0.f;
    #pragma unroll
    for (int k = 0; k < 16; ++k) {
        float ok = __shfl(v, k, 16);
        h2 = fmaf(ok, W2[k * 16 + j], h2);
    }
    hs2[node * 16 + j] = h2 * di;
}

// --- final: v = acc*dinv + b2; log_softmax over 16 classes ---
__global__ void k_final(const float* __restrict__ acc, const float* __restrict__ dinv,
                        const float* __restrict__ b2, float* __restrict__ out, int n)
{
    int t = blockIdx.x * blockDim.x + threadIdx.x;
    int node = t >> 4, j = t & 15;
    if (node >= n) return;
    float v = acc[node * 16 + j] * dinv[node] + b2[j];
    float m = v;
    #pragma unroll
    for (int off = 8; off >= 1; off >>= 1) m = fmaxf(m, __shfl_xor(m, off));
    float e = expf(v - m);
    float s = e;
    #pragma unroll
    for (int off = 8; off >= 1; off >>= 1) s += __shfl_xor(s, off);
    out[node * 16 + j] = v - m - logf(s);
}

extern "C" void kernel_launch(void* const* d_in, const int* in_sizes, int n_in,
                              void* d_out, int out_size, void* d_ws, size_t ws_size,
                              hipStream_t stream)
{
    const float* x  = (const float*)d_in[0];
    const int*   ei = (const int*)d_in[1];   // [2, E]: row then col
    const float* W1 = (const float*)d_in[2];
    const float* b1 = (const float*)d_in[3];
    const float* W2 = (const float*)d_in[4];
    const float* b2 = (const float*)d_in[5];
    float* out = (float*)d_out;

    const int n  = in_sizes[0] / F_IN;       // 100000
    const int E  = in_sizes[1] / 2;          // 3.2M
    const int NB = (n + BNODES - 1) >> BSH;  // 1563 buckets

    // workspace: cbin | cbase | cpos | dinv | entries | hs   (acc lives in d_out)
    char* ws = (char*)d_ws;
    size_t szB = (((size_t)NB * 4) + 511) & ~(size_t)511;
    size_t szN = (((size_t)n  * 4) + 511) & ~(size_t)511;
    int*   cbin    = (int*)(ws);
    int*   cbase   = (int*)(ws + szB);
    int*   cpos    = (int*)(ws + 2 * szB);
    float* dinv    = (float*)(ws + 3 * szB);
    int*   entries = (int*)(ws + 3 * szB + szN);
    float* hs      = (float*)(ws + 3 * szB + szN + (((size_t)E * 4 + 511) & ~(size_t)511));
    float* acc     = out;

    hipMemsetAsync(cbin, 0, (size_t)NB * sizeof(int), stream);
    k_hist <<<(E + 255) / 256, 256, 0, stream>>>(ei + E, cbin, E);
    k_scanb<<<1, 1024, 0, stream>>>(cbin, cbase, cpos, NB);
    k_bin  <<<(E + 255) / 256, 256, 0, stream>>>(ei, ei + E, cpos, entries, E);
    k_bdeg <<<NB, 256, 0, stream>>>(entries, cbase, cpos, dinv, n);

    // layer 1
    k_gemm1   <<<2048, 256, 0, stream>>>(x, W1, dinv, hs, n);
    k_gather_b<<<NB, 256, 0, stream>>>(entries, cbase, cpos, hs, acc, n);

    // layer 2
    k_gemm2   <<<(n * 16 + 255) / 256, 256, 0, stream>>>(acc, hs, dinv, b1, W2, n);
    k_gather_b<<<NB, 256, 0, stream>>>(entries, cbase, cpos, hs, acc, n);

    // epilogue
    k_final   <<<(n * 16 + 255) / 256, 256, 0, stream>>>(acc, dinv, b2, out, n);
}

// Round 4
// 779.504 us; speedup vs baseline: 2.4556x; 2.4556x over previous
//
#include <hip/hip_runtime.h>
#include <hip/hip_bf16.h>
#include <hip/hip_fp16.h>

#define F_IN 512

// --- in-degree count over col (int atomics) ---
__global__ void k_deg(const int* __restrict__ col, int* __restrict__ deg, int E) {
    int i = blockIdx.x * blockDim.x + threadIdx.x;
    if (i < E) atomicAdd(&deg[col[i]], 1);
}

// --- dinv = rsqrt(deg + 1)   (in-place int -> float) ---
__global__ void k_dinv(float* __restrict__ buf, int n) {
    int i = blockIdx.x * blockDim.x + threadIdx.x;
    if (i < n) {
        int d = ((const int*)buf)[i] + 1;   // +1 self-loop
        buf[i] = rsqrtf((float)d);
    }
}

// --- hs = (x @ W1) * dinv[node] stored f16; acc initialized to hs (self-loop) ---
// wave-per-node; W1 (512x16) in 128 VGPRs/lane; LDS transpose-reduce.
__global__ __launch_bounds__(256) void k_gemm1(
    const float* __restrict__ x, const float* __restrict__ W1,
    const float* __restrict__ dinv, __half2* __restrict__ hs,
    __half2* __restrict__ acc, int n)
{
    __shared__ float red[4][64 * 17];       // pad 17: 2-way bank alias = free
    const int lane = threadIdx.x & 63;
    const int wib  = threadIdx.x >> 6;
    const int wave = blockIdx.x * (blockDim.x >> 6) + wib;
    const int nw   = gridDim.x * (blockDim.x >> 6);
    float* rb = red[wib];

    float w[128];
    #pragma unroll
    for (int i = 0; i < 32; ++i) {
        float4 t = ((const float4*)W1)[lane * 32 + i];
        w[4*i+0] = t.x; w[4*i+1] = t.y; w[4*i+2] = t.z; w[4*i+3] = t.w;
    }
    const int q  = lane >> 4;
    const int jj = lane & 15;

    for (int node = wave; node < n; node += nw) {
        const float4* xr = (const float4*)(x + (size_t)node * F_IN);
        float4 a = xr[lane * 2];
        float4 b = xr[lane * 2 + 1];
        float xs[8] = {a.x, a.y, a.z, a.w, b.x, b.y, b.z, b.w};

        float p[16];
        #pragma unroll
        for (int j = 0; j < 16; ++j) p[j] = 0.f;
        #pragma unroll
        for (int i = 0; i < 8; ++i)
            #pragma unroll
            for (int j = 0; j < 16; ++j)
                p[j] = fmaf(xs[i], w[i * 16 + j], p[j]);

        #pragma unroll
        for (int j = 0; j < 16; ++j) rb[lane * 17 + j] = p[j];
        __asm__ volatile("s_waitcnt lgkmcnt(0)" ::: "memory");
        float s = 0.f;
        #pragma unroll
        for (int i = 0; i < 16; ++i) s += rb[(q * 16 + i) * 17 + jj];
        s += __shfl_down(s, 32);
        s += __shfl_down(s, 16);

        float di = dinv[node];
        float sv = s * di;
        float sn = __shfl_down(sv, 1);      // lanes 0..14 read active lanes 1..15
        if (lane < 16 && (lane & 1) == 0) {
            __half2 hv = __halves2half2(__float2half(sv), __float2half(sn));
            hs [node * 8 + (lane >> 1)] = hv;
            acc[node * 8 + (lane >> 1)] = hv;
        }
    }
}

// --- acc[col[e]] += hs[row[e]], 8 lanes/edge, packed f16 HW atomics ---
__global__ void k_scatter(const int* __restrict__ row, const int* __restrict__ col,
                          const __half2* __restrict__ hs, __half2* __restrict__ acc, int E)
{
    int t = blockIdx.x * blockDim.x + threadIdx.x;
    int e = t >> 3;
    if (e < E) {
        int j = t & 7;
        int r = row[e], c = col[e];
        unsafeAtomicAdd(&acc[c * 8 + j], hs[r * 8 + j]);   // global_atomic_pk_add_f16
    }
}

// --- layer-2: v = relu(acc*dinv + b1); hs2 = (v @ W2) * dinv (f16); acc2 init ---
__global__ void k_gemm2(const __half* __restrict__ acc, __half2* __restrict__ hs2,
                        __half2* __restrict__ acc2, const float* __restrict__ dinv,
                        const float* __restrict__ b1, const float* __restrict__ W2,
                        int n)
{
    int t = blockIdx.x * blockDim.x + threadIdx.x;
    int node = t >> 4, j = t & 15;
    if (node >= n) return;
    float di = dinv[node];
    float v = fmaxf(__half2float(acc[node * 16 + j]) * di + b1[j], 0.f);
    float h2 = 0.f;
    #pragma unroll
    for (int k = 0; k < 16; ++k) {
        float ok = __shfl(v, k, 16);
        h2 = fmaf(ok, W2[k * 16 + j], h2);
    }
    float o  = h2 * di;
    float o1 = __shfl_down(o, 1);
    if ((j & 1) == 0) {
        __half2 hv = __halves2half2(__float2half(o), __float2half(o1));
        hs2 [node * 8 + (j >> 1)] = hv;
        acc2[node * 8 + (j >> 1)] = hv;
    }
}

// --- final: v = acc2*dinv + b2; log_softmax over 16 classes; fp32 out ---
__global__ void k_final(const __half* __restrict__ acc2, const float* __restrict__ dinv,
                        const float* __restrict__ b2, float* __restrict__ out, int n)
{
    int t = blockIdx.x * blockDim.x + threadIdx.x;
    int node = t >> 4, j = t & 15;
    if (node >= n) return;
    float v = __half2float(acc2[node * 16 + j]) * dinv[node] + b2[j];
    float m = v;
    #pragma unroll
    for (int off = 8; off >= 1; off >>= 1) m = fmaxf(m, __shfl_xor(m, off));
    float e = expf(v - m);
    float s = e;
    #pragma unroll
    for (int off = 8; off >= 1; off >>= 1) s += __shfl_xor(s, off);
    out[node * 16 + j] = v - m - logf(s);
}

extern "C" void kernel_launch(void* const* d_in, const int* in_sizes, int n_in,
                              void* d_out, int out_size, void* d_ws, size_t ws_size,
                              hipStream_t stream)
{
    const float* x  = (const float*)d_in[0];
    const int*   ei = (const int*)d_in[1];   // [2, E]: row then col
    const float* W1 = (const float*)d_in[2];
    const float* b1 = (const float*)d_in[3];
    const float* W2 = (const float*)d_in[4];
    const float* b2 = (const float*)d_in[5];
    float* out = (float*)d_out;

    const int n = in_sizes[0] / F_IN;        // 100000
    const int E = in_sizes[1] / 2;           // 3.2M

    // workspace: dinv (n f32) | hs (n*16 f16) | acc (n*16 f16) | acc2 (n*16 f16)
    // hs2 reuses hs (hs dead after first scatter).
    char* ws = (char*)d_ws;
    size_t szN = (((size_t)n * 4) + 511) & ~(size_t)511;
    size_t szH = (((size_t)n * 16 * 2) + 511) & ~(size_t)511;
    float*   dinv = (float*)(ws);
    __half2* hs   = (__half2*)(ws + szN);
    __half2* acc  = (__half2*)(ws + szN + szH);
    __half2* acc2 = (__half2*)(ws + szN + 2 * szH);

    hipMemsetAsync(dinv, 0, (size_t)n * sizeof(int), stream);
    k_deg <<<(E + 255) / 256, 256, 0, stream>>>(ei + E, (int*)dinv, E);
    k_dinv<<<(n + 255) / 256, 256, 0, stream>>>(dinv, n);

    // layer 1
    k_gemm1  <<<2048, 256, 0, stream>>>(x, W1, dinv, hs, acc, n);
    k_scatter<<<(E * 8 + 255) / 256, 256, 0, stream>>>(ei, ei + E, hs, acc, E);

    // layer 2 (hs2 reuses hs buffer)
    k_gemm2  <<<(n * 16 + 255) / 256, 256, 0, stream>>>((const __half*)acc, hs, acc2,
                                                        dinv, b1, W2, n);
    k_scatter<<<(E * 8 + 255) / 256, 256, 0, stream>>>(ei, ei + E, hs, acc2, E);

    // epilogue
    k_final  <<<(n * 16 + 255) / 256, 256, 0, stream>>>((const __half*)acc2, dinv, b2, out, n);
}